// Round 18
// baseline (399.375 us; speedup 1.0000x reference)
//
#include <hip/hip_runtime.h>
#include <hip/hip_bf16.h>
#include <stdint.h>

// Round 18: persistent-weight blocks. r16/r17 falsified barrier-count and
// occupancy theories; the shared trait of all ~200us designs was per-step
// weight staging + barriers coupling all waves. Here: 1 block/CU (grid 256,
// 1024 thr = 16 waves), 1024 rows/block (4 chunks x 256). W1p+Wip staged to
// LDS ONCE; phases 1-2 are barrier-free (features stream, weights resident).
// Only GEMM2's W2T double-buffers through 2x16KB (6 cheap bars/chunk).
// LDS 148480B (<=160KB). 16 rows/wave pi-design regs <=128 -> 4 waves/SIMD.
// Math identical to r14-r17 (PASS, absmax 0.03125).

typedef __attribute__((ext_vector_type(8))) short short8;
typedef __attribute__((ext_vector_type(4))) float float4v;

#define MFMA16 __builtin_amdgcn_mfma_f32_16x16x32_bf16

__device__ __align__(16) uint16_t g_wpack[98816];

static __device__ __forceinline__ void gl_lds16(const void* g, void* l) {
    __builtin_amdgcn_global_load_lds(
        (const __attribute__((address_space(1))) unsigned int*)g,
        (__attribute__((address_space(3))) unsigned int*)l, 16, 0, 0);
}

static __device__ __forceinline__ uint16_t f2bf(float f) {
    __hip_bfloat16 h = __float2bfloat16(f);
    return *reinterpret_cast<uint16_t*>(&h);
}

static __device__ __forceinline__ int pk2(float lo, float hi) {
    __hip_bfloat162 b = __float22bfloat162_rn(make_float2(lo, hi));
    int u; __builtin_memcpy(&u, &b, 4); return u;
}

static __device__ __forceinline__ short8 cvt8(float4v x0, float4v x1) {
    union { __hip_bfloat162 b2[4]; short8 s; } u;
    u.b2[0] = __float22bfloat162_rn(make_float2(x0[0], x0[1]));
    u.b2[1] = __float22bfloat162_rn(make_float2(x0[2], x0[3]));
    u.b2[2] = __float22bfloat162_rn(make_float2(x1[0], x1[1]));
    u.b2[3] = __float22bfloat162_rn(make_float2(x1[2], x1[3]));
    return u.s;
}

// ---- weight packing (identical to r15-r17) ----
// W1p: 9kt x 9nt std frags (K=288 pad, N=144 pad) @byte 0      (82944B)
// W2Tp: pi-packed transposed, KT-MAJOR: frag = kt*16+nt @byte 82944 (81920B)
// Wip: 16kt x 2nt std frags (K=512, N=32 pad) @byte 164864 (32768B)
__global__ __launch_bounds__(256) void pack_weights(
    const float* __restrict__ W1, const float* __restrict__ W2,
    const float* __restrict__ Wi)
{
    int e = blockIdx.x * 256 + threadIdx.x;
    if (e >= 98816) return;
    if (e >= 41472 && e < 82432) {            // W2^T pi-packed, kt-major
        int le = e - 41472;
        int i = le & 7, lane = (le >> 3) & 63, frag = le >> 9;   // 0..79
        int kt = frag >> 4, nt = frag & 15;
        int k = kt * 32 + ((i >= 4) ? 16 : 0) + ((lane >> 4) << 2) + (i & 3);
        int n = nt * 16 + (lane & 15);
        float v = (k < 140) ? W2[k * 256 + n] : 0.0f;
        g_wpack[e] = f2bf(v);
        return;
    }
    const float* W; int NT, Kr, Nr, ld, le, base;
    if (e < 41472) { W = W1; NT = 9; Kr = 280; Nr = 140; ld = 140; le = e;         base = 0; }
    else           { W = Wi; NT = 2; Kr = 512; Nr = 24;  ld = 24;  le = e - 82432; base = 82432; }
    int i = le & 7, lane = (le >> 3) & 63, frag = le >> 9;
    int kt = frag / NT, nt = frag - kt * NT;
    int k = kt * 32 + ((lane >> 4) << 3) + i;
    int n = nt * 16 + (lane & 15);
    float v = (k < Kr && n < Nr) ? W[k * ld + n] : 0.0f;
    g_wpack[base + le] = f2bf(v);
}

// ---- main kernel: 1024 threads = 16 waves, 16 rows/wave, 4 chunks ----
__global__ __launch_bounds__(1024, 4) void icm_main(
    const float* __restrict__ cf, const float* __restrict__ nf,
    const int* __restrict__ act,
    const float* __restrict__ b1, const float* __restrict__ b2,
    const float* __restrict__ bi,
    float* __restrict__ out)
{
    // [0,82944)        W1L  (persistent W1 frags)
    // [82944,115712)   WiL  (persistent Wi frags)
    // [115712,132096)  wstA / [132096,148480) wstB : W2T 16KB windows
    __shared__ __align__(16) char smem[148480];
    char* W1L  = smem;
    char* WiL  = smem + 82944;
    char* wstA = smem + 115712;
    char* wstB = smem + 132096;

    const int tid  = threadIdx.x;
    const int wave = tid >> 6;    // 0..15
    const int lane = tid & 63;
    const int lhi  = lane >> 4;
    const int llo  = lane & 15;

    const char* gw = (const char*)g_wpack;
    const float4v fz = {0.f, 0.f, 0.f, 0.f};

    // ---- one-time persistent weight stage (W1p + Wip) ----
    #pragma unroll
    for (int j = 0; j < 6; ++j) {
        int b = j * 16384 + wave * 1024;
        if (b < 82944) gl_lds16(gw + b + lane * 16, W1L + b);
    }
    #pragma unroll
    for (int j = 0; j < 2; ++j) {
        int b = j * 16384 + wave * 1024;
        gl_lds16(gw + 164864 + b + lane * 16, WiL + b);
    }
    auto stage16 = [&](char* dst, const char* src) {   // one 16KB window
        int b = wave * 1024;
        gl_lds16(src + b + lane * 16, dst + b);
    };
    __syncthreads();   // persistent weights resident

    #pragma unroll 1
    for (int c = 0; c < 4; ++c) {
        const long rowbase = (long)blockIdx.x * 1024 + c * 256 + wave * 16;

        stage16(wstA, gw + 82944);             // W2T kt0 (flies under ph1/2)

        // actions for this chunk
        int i0, i1, i2;
        {
            long r = rowbase + llo;
            long f = r >> 6; int n = (int)(r & 63);
            i0 = act[(f * 3 + 0) * 64 + n];
            i1 = act[(f * 3 + 1) * 64 + n] + 8;
            i2 = act[(f * 3 + 2) * 64 + n] + 16;
        }

        float4v acc1[9];
        float4v acc3[2];
        #pragma unroll
        for (int n = 0; n < 9; ++n) acc1[n] = fz;
        acc3[0] = fz; acc3[1] = fz;

        const float* cfb = cf + (rowbase + llo) * 256 + lhi * 8;
        float4v pa0, pa1, pb0, pb1;

        // ===== Phase 1: GEMM1(sw)+GEMM3a(sw), barrier-free =====
        pa0 = *(const float4v*)(cfb);      pa1 = *(const float4v*)(cfb + 4);
        pb0 = *(const float4v*)(cfb + 32); pb1 = *(const float4v*)(cfb + 36);
        #pragma unroll 1
        for (int kt = 0; kt < 8; ++kt) {
            short8 a = (kt & 1) ? cvt8(pb0, pb1) : cvt8(pa0, pa1);
            if (kt <= 5) {
                int o = (kt + 2) * 32;
                if (kt & 1) { pb0 = *(const float4v*)(cfb + o); pb1 = *(const float4v*)(cfb + o + 4); }
                else        { pa0 = *(const float4v*)(cfb + o); pa1 = *(const float4v*)(cfb + o + 4); }
            }
            const char* base = W1L + kt * 9216;
            #pragma unroll
            for (int nt = 0; nt < 9; ++nt) {
                short8 bf = *(const short8*)(base + (nt << 10) + (lane << 4));
                acc1[nt] = MFMA16(bf, a, acc1[nt], 0, 0, 0);   // swapped
            }
            #pragma unroll
            for (int nt = 0; nt < 2; ++nt) {
                short8 bf = *(const short8*)(WiL + (((kt << 1) + nt) << 10) + (lane << 4));
                acc3[nt] = MFMA16(bf, a, acc3[nt], 0, 0, 0);   // swapped
            }
        }
        {   // kt = 8: one-hot action K-tile
            short8 a;
            #pragma unroll
            for (int i = 0; i < 8; ++i) {
                int kk = lhi * 8 + i;
                a[i] = (kk == i0 || kk == i1 || kk == i2) ? (short)0x3F80 : (short)0;
            }
            const char* base = W1L + 8 * 9216;
            #pragma unroll
            for (int nt = 0; nt < 9; ++nt) {
                short8 bf = *(const short8*)(base + (nt << 10) + (lane << 4));
                acc1[nt] = MFMA16(bf, a, acc1[nt], 0, 0, 0);
            }
        }

        // ---- epilogue: acc1 -> hb (bias + leaky + cvt, pi-order) ----
        short8 hb[5];
        #pragma unroll
        for (int kt = 0; kt < 5; ++kt) {
            int cLo = 2 * kt * 16 + lhi * 4;
            int cHi = (2 * kt + 1) * 16 + lhi * 4;
            if (cLo > 136) cLo = 136;
            float4v bLo = *(const float4v*)(b1 + cLo);
            float4v bHi = (kt < 4) ? *(const float4v*)(b1 + cHi) : fz;
            union { int d[4]; short8 s; } t;
            float v0 = acc1[2 * kt][0] + bLo[0]; v0 = v0 > 0.f ? v0 : 0.1f * v0;
            float v1 = acc1[2 * kt][1] + bLo[1]; v1 = v1 > 0.f ? v1 : 0.1f * v1;
            float v2 = acc1[2 * kt][2] + bLo[2]; v2 = v2 > 0.f ? v2 : 0.1f * v2;
            float v3 = acc1[2 * kt][3] + bLo[3]; v3 = v3 > 0.f ? v3 : 0.1f * v3;
            t.d[0] = pk2(v0, v1);
            t.d[1] = pk2(v2, v3);
            if (kt < 4) {
                float w0 = acc1[2 * kt + 1][0] + bHi[0]; w0 = w0 > 0.f ? w0 : 0.1f * w0;
                float w1 = acc1[2 * kt + 1][1] + bHi[1]; w1 = w1 > 0.f ? w1 : 0.1f * w1;
                float w2 = acc1[2 * kt + 1][2] + bHi[2]; w2 = w2 > 0.f ? w2 : 0.1f * w2;
                float w3 = acc1[2 * kt + 1][3] + bHi[3]; w3 = w3 > 0.f ? w3 : 0.1f * w3;
                t.d[2] = pk2(w0, w1);
                t.d[3] = pk2(w2, w3);
            } else { t.d[2] = 0; t.d[3] = 0; }
            hb[kt] = t.s;
        }

        // ===== Phase 2: GEMM3b(sw) over nf, barrier-free =====
        const float* nfb = nf + (rowbase + llo) * 256 + lhi * 8;
        pa0 = *(const float4v*)(nfb);      pa1 = *(const float4v*)(nfb + 4);
        pb0 = *(const float4v*)(nfb + 32); pb1 = *(const float4v*)(nfb + 36);
        #pragma unroll 1
        for (int kt = 0; kt < 8; ++kt) {
            short8 a = (kt & 1) ? cvt8(pb0, pb1) : cvt8(pa0, pa1);
            if (kt <= 5) {
                int o = (kt + 2) * 32;
                if (kt & 1) { pb0 = *(const float4v*)(nfb + o); pb1 = *(const float4v*)(nfb + o + 4); }
                else        { pa0 = *(const float4v*)(nfb + o); pa1 = *(const float4v*)(nfb + o + 4); }
            }
            #pragma unroll
            for (int nt = 0; nt < 2; ++nt) {
                int f = 16 + 2 * kt + nt;      // Wi frags 16..31
                short8 bf = *(const short8*)(WiL + (f << 10) + (lane << 4));
                acc3[nt] = MFMA16(bf, a, acc3[nt], 0, 0, 0);   // swapped
            }
        }
        // out1^T stores
        float* out2 = out + 67108864L;
        #pragma unroll
        for (int nt = 0; nt < 2; ++nt) {
            if (nt == 0 || lhi < 2) {          // cols < 24 only
                float4v biv = *(const float4v*)(bi + nt * 16 + lhi * 4);
                long row = rowbase + llo;
                float4v v = acc3[nt];
                v[0] += biv[0]; v[1] += biv[1]; v[2] += biv[2]; v[3] += biv[3];
                *(float4v*)(out2 + row * 24 + nt * 16 + lhi * 4) = v;
            }
        }
        __syncthreads();                       // bar1: W2T kt0 ready

        // ===== Phase 3: GEMM2 via pi-identity, 16KB windows =====
        float4v acc2[16];
        #pragma unroll
        for (int n = 0; n < 16; ++n) acc2[n] = fz;

        #pragma unroll 1
        for (int kt = 0; kt < 5; ++kt) {
            if (kt < 4)
                stage16((kt & 1) ? wstA : wstB, gw + 82944 + (kt + 1) * 16384);
            const char* wb = (kt & 1) ? wstB : wstA;
            #pragma unroll
            for (int n = 0; n < 16; ++n) {
                short8 bf = *(const short8*)(wb + (n << 10) + (lane << 4));
                acc2[n] = MFMA16(bf, hb[kt], acc2[n], 0, 0, 0);
            }
            __syncthreads();                   // bars 2..6
        }

        // out0^T stores (no LDS -> may overlap next chunk's work)
        #pragma unroll
        for (int n = 0; n < 16; ++n) {
            float4v b2v = *(const float4v*)(b2 + n * 16 + lhi * 4);
            long row = rowbase + llo;
            float4v v = acc2[n];
            v[0] += b2v[0]; v[1] += b2v[1]; v[2] += b2v[2]; v[3] += b2v[3];
            *(float4v*)(out + row * 256 + n * 16 + lhi * 4) = v;
        }
    }
}

extern "C" void kernel_launch(void* const* d_in, const int* in_sizes, int n_in,
                              void* d_out, int out_size, void* d_ws, size_t ws_size,
                              hipStream_t stream) {
    const float *cf = nullptr, *nf = nullptr, *W1 = nullptr, *b1 = nullptr;
    const float *W2 = nullptr, *b2 = nullptr, *Wi = nullptr, *bi = nullptr;
    const int *ac = nullptr;
    for (int i = 0; i < n_in; ++i) {
        int s = in_sizes[i];
        const void* p = d_in[i];
        switch (s) {
            case 67108864: if (!cf) cf = (const float*)p; else nf = (const float*)p; break;
            case 786432:   ac = (const int*)p;   break;
            case 39200:    W1 = (const float*)p; break;
            case 140:      b1 = (const float*)p; break;
            case 35840:    W2 = (const float*)p; break;
            case 256:      b2 = (const float*)p; break;
            case 12288:    Wi = (const float*)p; break;
            case 24:       bi = (const float*)p; break;
            default: break;
        }
    }
    float* ob = (float*)d_out;

    pack_weights<<<386, 256, 0, stream>>>(W1, W2, Wi);
    icm_main<<<256, 1024, 0, stream>>>(cf, nf, ac, b1, b2, bi, ob);
}

// Round 19
// 189.130 us; speedup vs baseline: 2.1116x; 2.1116x over previous
//
#include <hip/hip_runtime.h>
#include <hip/hip_bf16.h>
#include <stdint.h>

// Round 19: corrected clean-4-waves/SIMD experiment. r17/r18 never ran clean:
// acc2[16]=64 AGPR exhausted the 128-reg budget (VGPR_Count 64 + spill).
// This round: 512-thr blocks (8 waves x 16 rows), 2 blocks/CU, LDS 2x32KB;
// MERGED cf/nf streaming (GEMM1+GEMM3a+GEMM3b share one kt loop -> 2 feature
// streams x 2-deep = 8 loads in flight/wave, 2x r17); GEMM2 strictly 2-pass
// (acc2[8]=32 AGPR, 8KB pass-half W2T windows). Peak regs ~106 <= 128.
// Math = verified pi-identity lineage (r14-r18), bit-identical (0.03125).

typedef __attribute__((ext_vector_type(8))) short short8;
typedef __attribute__((ext_vector_type(4))) float float4v;

#define MFMA16 __builtin_amdgcn_mfma_f32_16x16x32_bf16

__device__ __align__(16) uint16_t g_wpack[98816];

static __device__ __forceinline__ void gl_lds16(const void* g, void* l) {
    __builtin_amdgcn_global_load_lds(
        (const __attribute__((address_space(1))) unsigned int*)g,
        (__attribute__((address_space(3))) unsigned int*)l, 16, 0, 0);
}

static __device__ __forceinline__ uint16_t f2bf(float f) {
    __hip_bfloat16 h = __float2bfloat16(f);
    return *reinterpret_cast<uint16_t*>(&h);
}

static __device__ __forceinline__ int pk2(float lo, float hi) {
    __hip_bfloat162 b = __float22bfloat162_rn(make_float2(lo, hi));
    int u; __builtin_memcpy(&u, &b, 4); return u;
}

static __device__ __forceinline__ short8 cvt8(float4v x0, float4v x1) {
    union { __hip_bfloat162 b2[4]; short8 s; } u;
    u.b2[0] = __float22bfloat162_rn(make_float2(x0[0], x0[1]));
    u.b2[1] = __float22bfloat162_rn(make_float2(x0[2], x0[3]));
    u.b2[2] = __float22bfloat162_rn(make_float2(x1[0], x1[1]));
    u.b2[3] = __float22bfloat162_rn(make_float2(x1[2], x1[3]));
    return u.s;
}

// ---- weight packing (identical to r15-r18) ----
// W1p: 9kt x 9nt std frags (K=288 pad, N=144 pad) @byte 0      (82944B)
// W2Tp: pi-packed transposed, KT-MAJOR: frag = kt*16+nt @byte 82944 (81920B)
// Wip: 16kt x 2nt std frags (K=512, N=32 pad) @byte 164864 (32768B)
__global__ __launch_bounds__(256) void pack_weights(
    const float* __restrict__ W1, const float* __restrict__ W2,
    const float* __restrict__ Wi)
{
    int e = blockIdx.x * 256 + threadIdx.x;
    if (e >= 98816) return;
    if (e >= 41472 && e < 82432) {            // W2^T pi-packed, kt-major
        int le = e - 41472;
        int i = le & 7, lane = (le >> 3) & 63, frag = le >> 9;   // 0..79
        int kt = frag >> 4, nt = frag & 15;
        int k = kt * 32 + ((i >= 4) ? 16 : 0) + ((lane >> 4) << 2) + (i & 3);
        int n = nt * 16 + (lane & 15);
        float v = (k < 140) ? W2[k * 256 + n] : 0.0f;
        g_wpack[e] = f2bf(v);
        return;
    }
    const float* W; int NT, Kr, Nr, ld, le, base;
    if (e < 41472) { W = W1; NT = 9; Kr = 280; Nr = 140; ld = 140; le = e;         base = 0; }
    else           { W = Wi; NT = 2; Kr = 512; Nr = 24;  ld = 24;  le = e - 82432; base = 82432; }
    int i = le & 7, lane = (le >> 3) & 63, frag = le >> 9;
    int kt = frag / NT, nt = frag - kt * NT;
    int k = kt * 32 + ((lane >> 4) << 3) + i;
    int n = nt * 16 + (lane & 15);
    float v = (k < Kr && n < Nr) ? W[k * ld + n] : 0.0f;
    g_wpack[base + le] = f2bf(v);
}

// ---- main kernel: 512 threads = 8 waves, 16 rows/wave, merged streams ----
__global__ __launch_bounds__(512, 4) void icm_main(
    const float* __restrict__ cf, const float* __restrict__ nf,
    const int* __restrict__ act,
    const float* __restrict__ b1, const float* __restrict__ b2,
    const float* __restrict__ bi,
    float* __restrict__ out)
{
    __shared__ __align__(16) char smem[65536];
    char* bufA = smem;
    char* bufB = smem + 32768;

    const int tid  = threadIdx.x;
    const int wave = tid >> 6;    // 0..7
    const int lane = tid & 63;
    const int lhi  = lane >> 4;
    const int llo  = lane & 15;

    const long rowbase = (long)blockIdx.x * 128 + wave * 16;
    const char* gw = (const char*)g_wpack;
    const float4v fz = {0.f, 0.f, 0.f, 0.f};

    // merged kt-slot = 13312B: W1(kt)[0,9216) + Wi-lo(kt)[9216,11264)
    //                           + Wi-hi(kt)[11264,13312)
    auto stage_slot = [&](char* dst, int kt) {
        const char* w1b = gw + kt * 9216;
        const char* wlo = gw + 164864 + kt * 2048;
        const char* whi = gw + 181248 + kt * 2048;
        #pragma unroll
        for (int k = 0; k < 2; ++k) {
            int b = k * 8192 + wave * 1024;
            if (b < 13312) {
                const char* src = (b < 9216) ? (w1b + b)
                                : (b < 11264) ? (wlo + (b - 9216))
                                              : (whi + (b - 11264));
                gl_lds16(src + lane * 16, dst + b);
            }
        }
    };
    auto stage8 = [&](char* dst, const char* src) {    // 8KB, 8 waves
        int b = wave * 1024;
        gl_lds16(src + b + lane * 16, dst + b);
    };

    // actions
    int i0, i1, i2;
    {
        long r = rowbase + llo;
        long f = r >> 6; int n = (int)(r & 63);
        i0 = act[(f * 3 + 0) * 64 + n];
        i1 = act[(f * 3 + 1) * 64 + n] + 8;
        i2 = act[(f * 3 + 2) * 64 + n] + 16;
    }

    float4v acc1[9];         // h^T
    float4v acc3[2];         // out1^T (both cf and nf halves accumulate here)
    #pragma unroll
    for (int n = 0; n < 9; ++n) acc1[n] = fz;
    acc3[0] = fz; acc3[1] = fz;

    const float* cfb = cf + (rowbase + llo) * 256 + lhi * 8;
    const float* nfb = nf + (rowbase + llo) * 256 + lhi * 8;

    float4v pa0, pa1, pb0, pb1;   // cf rolling slots
    float4v qa0, qa1, qb0, qb1;   // nf rolling slots

    // merged step: 9 MFMA acc1(cf) + 2 acc3(Wi-lo,cf) + 2 acc3(Wi-hi,nf)
    auto g1m = [&](const char* base, int kt) {
        short8 ac = (kt & 1) ? cvt8(pb0, pb1) : cvt8(pa0, pa1);
        short8 an = (kt & 1) ? cvt8(qb0, qb1) : cvt8(qa0, qa1);
        if (kt <= 5) {
            int o = (kt + 2) * 32;
            if (kt & 1) {
                pb0 = *(const float4v*)(cfb + o); pb1 = *(const float4v*)(cfb + o + 4);
                qb0 = *(const float4v*)(nfb + o); qb1 = *(const float4v*)(nfb + o + 4);
            } else {
                pa0 = *(const float4v*)(cfb + o); pa1 = *(const float4v*)(cfb + o + 4);
                qa0 = *(const float4v*)(nfb + o); qa1 = *(const float4v*)(nfb + o + 4);
            }
        }
        #pragma unroll
        for (int nt = 0; nt < 9; ++nt) {
            short8 bf = *(const short8*)(base + (nt << 10) + (lane << 4));
            acc1[nt] = MFMA16(bf, ac, acc1[nt], 0, 0, 0);   // swapped
        }
        #pragma unroll
        for (int nt = 0; nt < 2; ++nt) {
            short8 bf = *(const short8*)(base + 9216 + (nt << 10) + (lane << 4));
            acc3[nt] = MFMA16(bf, ac, acc3[nt], 0, 0, 0);   // Wi-lo x cf
        }
        #pragma unroll
        for (int nt = 0; nt < 2; ++nt) {
            short8 bf = *(const short8*)(base + 11264 + (nt << 10) + (lane << 4));
            acc3[nt] = MFMA16(bf, an, acc3[nt], 0, 0, 0);   // Wi-hi x nf
        }
    };

    // ===== prologue: stage {kt0,kt1} -> bufA; features kt0,kt1 both streams
    stage_slot(bufA, 0); stage_slot(bufA + 13312, 1);
    pa0 = *(const float4v*)(cfb);      pa1 = *(const float4v*)(cfb + 4);
    pb0 = *(const float4v*)(cfb + 32); pb1 = *(const float4v*)(cfb + 36);
    qa0 = *(const float4v*)(nfb);      qa1 = *(const float4v*)(nfb + 4);
    qb0 = *(const float4v*)(nfb + 32); qb1 = *(const float4v*)(nfb + 36);
    __syncthreads();                                        // bar 1

    stage_slot(bufB, 2); stage_slot(bufB + 13312, 3);
    g1m(bufA, 0); g1m(bufA + 13312, 1);
    __syncthreads();                                        // bar 2

    stage_slot(bufA, 4); stage_slot(bufA + 13312, 5);
    g1m(bufB, 2); g1m(bufB + 13312, 3);
    __syncthreads();                                        // bar 3

    stage_slot(bufB, 6); stage_slot(bufB + 13312, 7);
    g1m(bufA, 4); g1m(bufA + 13312, 5);
    __syncthreads();                                        // bar 4

    stage_slot(bufA, 8);                   // kt8: W1 frags only (bytes <9216 used)
    g1m(bufB, 6); g1m(bufB + 13312, 7);
    __syncthreads();                                        // bar 5

    // ===== w4: one-hot K-tile from bufA; stage W2T {p0,kt0},{p0,kt1} -> bufB
    stage8(bufB, gw + 82944);                  // p0 kt0
    stage8(bufB + 8192, gw + 82944 + 16384);   // p0 kt1
    {
        short8 a;
        #pragma unroll
        for (int i = 0; i < 8; ++i) {
            int kk = lhi * 8 + i;
            a[i] = (kk == i0 || kk == i1 || kk == i2) ? (short)0x3F80 : (short)0;
        }
        #pragma unroll
        for (int nt = 0; nt < 9; ++nt) {
            short8 bf = *(const short8*)(bufA + (nt << 10) + (lane << 4));
            acc1[nt] = MFMA16(bf, a, acc1[nt], 0, 0, 0);
        }
    }
    // out1^T stores (acc3 complete after merged phase)
    float* out2 = out + 67108864L;
    #pragma unroll
    for (int nt = 0; nt < 2; ++nt) {
        if (nt == 0 || lhi < 2) {
            float4v biv = *(const float4v*)(bi + nt * 16 + lhi * 4);
            long row = rowbase + llo;
            float4v v = acc3[nt];
            v[0] += biv[0]; v[1] += biv[1]; v[2] += biv[2]; v[3] += biv[3];
            *(float4v*)(out2 + row * 24 + nt * 16 + lhi * 4) = v;
        }
    }
    // epilogue: acc1 -> hb (bias + leaky + cvt, pi-order)
    short8 hb[5];
    #pragma unroll
    for (int kt = 0; kt < 5; ++kt) {
        int cLo = 2 * kt * 16 + lhi * 4;
        int cHi = (2 * kt + 1) * 16 + lhi * 4;
        if (cLo > 136) cLo = 136;
        float4v bLo = *(const float4v*)(b1 + cLo);
        float4v bHi = (kt < 4) ? *(const float4v*)(b1 + cHi) : fz;
        union { int d[4]; short8 s; } t;
        float v0 = acc1[2 * kt][0] + bLo[0]; v0 = v0 > 0.f ? v0 : 0.1f * v0;
        float v1 = acc1[2 * kt][1] + bLo[1]; v1 = v1 > 0.f ? v1 : 0.1f * v1;
        float v2 = acc1[2 * kt][2] + bLo[2]; v2 = v2 > 0.f ? v2 : 0.1f * v2;
        float v3 = acc1[2 * kt][3] + bLo[3]; v3 = v3 > 0.f ? v3 : 0.1f * v3;
        t.d[0] = pk2(v0, v1);
        t.d[1] = pk2(v2, v3);
        if (kt < 4) {
            float w0 = acc1[2 * kt + 1][0] + bHi[0]; w0 = w0 > 0.f ? w0 : 0.1f * w0;
            float w1 = acc1[2 * kt + 1][1] + bHi[1]; w1 = w1 > 0.f ? w1 : 0.1f * w1;
            float w2 = acc1[2 * kt + 1][2] + bHi[2]; w2 = w2 > 0.f ? w2 : 0.1f * w2;
            float w3 = acc1[2 * kt + 1][3] + bHi[3]; w3 = w3 > 0.f ? w3 : 0.1f * w3;
            t.d[2] = pk2(w0, w1);
            t.d[3] = pk2(w2, w3);
        } else { t.d[2] = 0; t.d[3] = 0; }
        hb[kt] = t.s;
    }
    __syncthreads();                                        // bar 6

    // ===== phase 3: GEMM2 pi-identity, 2 passes (acc2[8]), 8KB windows =====
    auto g2 = [&](const char* wb, int kt, float4v* acc2) {
        #pragma unroll
        for (int n = 0; n < 8; ++n) {
            short8 bf = *(const short8*)(wb + (n << 10) + (lane << 4));
            acc2[n] = MFMA16(bf, hb[kt], acc2[n], 0, 0, 0);
        }
    };
    auto store_p = [&](int p, float4v* acc2) {
        #pragma unroll
        for (int n = 0; n < 8; ++n) {
            int nt = p * 8 + n;
            float4v b2v = *(const float4v*)(b2 + nt * 16 + lhi * 4);
            long row = rowbase + llo;
            float4v v = acc2[n];
            v[0] += b2v[0]; v[1] += b2v[1]; v[2] += b2v[2]; v[3] += b2v[3];
            *(float4v*)(out + row * 256 + nt * 16 + lhi * 4) = v;
        }
    };
    const char* w2t = gw + 82944;   // + kt*16384 + p*8192

    {   // pass 0
        float4v acc2[8];
        #pragma unroll
        for (int n = 0; n < 8; ++n) acc2[n] = fz;

        stage8(bufA, w2t + 2 * 16384);            // p0 kt2
        stage8(bufA + 8192, w2t + 3 * 16384);     // p0 kt3
        g2(bufB, 0, acc2); g2(bufB + 8192, 1, acc2);
        __syncthreads();                                    // bar 7

        stage8(bufB, w2t + 4 * 16384);            // p0 kt4
        stage8(bufB + 8192, w2t + 8192);          // p1 kt0
        g2(bufA, 2, acc2); g2(bufA + 8192, 3, acc2);
        __syncthreads();                                    // bar 8

        stage8(bufA, w2t + 16384 + 8192);         // p1 kt1
        stage8(bufA + 8192, w2t + 2 * 16384 + 8192); // p1 kt2
        g2(bufB, 4, acc2);
        store_p(0, acc2);
        __syncthreads();                                    // bar 9
    }
    {   // pass 1
        float4v acc2[8];
        #pragma unroll
        for (int n = 0; n < 8; ++n) acc2[n] = fz;

        stage8(bufB, w2t + 3 * 16384 + 8192);     // p1 kt3  (bufB[0..8K) free:
        g2(bufB + 8192, 0, acc2);                 //   p1kt0 lives at bufB+8192)
        g2(bufA, 1, acc2); g2(bufA + 8192, 2, acc2);
        __syncthreads();                                    // bar 10

        stage8(bufA, w2t + 4 * 16384 + 8192);     // p1 kt4
        g2(bufB, 3, acc2);
        __syncthreads();                                    // bar 11

        g2(bufA, 4, acc2);
        store_p(1, acc2);
    }
}

extern "C" void kernel_launch(void* const* d_in, const int* in_sizes, int n_in,
                              void* d_out, int out_size, void* d_ws, size_t ws_size,
                              hipStream_t stream) {
    const float *cf = nullptr, *nf = nullptr, *W1 = nullptr, *b1 = nullptr;
    const float *W2 = nullptr, *b2 = nullptr, *Wi = nullptr, *bi = nullptr;
    const int *ac = nullptr;
    for (int i = 0; i < n_in; ++i) {
        int s = in_sizes[i];
        const void* p = d_in[i];
        switch (s) {
            case 67108864: if (!cf) cf = (const float*)p; else nf = (const float*)p; break;
            case 786432:   ac = (const int*)p;   break;
            case 39200:    W1 = (const float*)p; break;
            case 140:      b1 = (const float*)p; break;
            case 35840:    W2 = (const float*)p; break;
            case 256:      b2 = (const float*)p; break;
            case 12288:    Wi = (const float*)p; break;
            case 24:       bi = (const float*)p; break;
            default: break;
        }
    }
    float* ob = (float*)d_out;

    pack_weights<<<386, 256, 0, stream>>>(W1, W2, Wi);
    icm_main<<<2048, 512, 0, stream>>>(cf, nf, ac, b1, b2, bi, ob);
}